// Round 13
// baseline (169.348 us; speedup 1.0000x reference)
//
#include <hip/hip_runtime.h>
#include <math.h>

#define EDIM 128
#define NHEAD 16
#define HDIM 8
#define SEQ 2048
#define BATCH 4
#define NROW (BATCH*SEQ)            // 8192
// -scale*log2(e): folded into Q at projection time so sigmoid = rcp(1+exp2(dot))
#define QNEG (-0.35355339059327373f * 1.4426950408889634f)

#if __has_builtin(__builtin_amdgcn_exp2f)
#define EXP2F(x) __builtin_amdgcn_exp2f(x)
#else
#define EXP2F(x) exp2f(x)
#endif
#define RCPF(x) __builtin_amdgcn_rcpf(x)

typedef __attribute__((ext_vector_type(8))) short short8v;
typedef __attribute__((ext_vector_type(4))) short short4v;
typedef __attribute__((ext_vector_type(4))) float float4v;

union U16x8 { uint4 u; short8v s; };
union U16x4 { uint2 u; short4v s; };

#if __has_builtin(__builtin_amdgcn_mfma_f32_16x16x16bf16_1k)
#define MFMA_PV(a,b,c) __builtin_amdgcn_mfma_f32_16x16x16bf16_1k(a,b,c,0,0,0)
#else
static __device__ __forceinline__ float4v mfma_pv_asm(short4v a, short4v b, float4v c) {
  float4v d;
  asm("v_mfma_f32_16x16x16_bf16 %0, %1, %2, %3" : "=v"(d) : "v"(a), "v"(b), "v"(c));
  return d;
}
#define MFMA_PV(a,b,c) mfma_pv_asm(a,b,c)
#endif

// pack two floats to bf16x2, round-to-nearest-even (values finite)
__device__ __forceinline__ unsigned pk_bf16(float a, float b) {
  unsigned ua = __float_as_uint(a), ub = __float_as_uint(b);
  unsigned lo = (ua + 0x7fffu + ((ua >> 16) & 1u)) >> 16;
  unsigned hi = (ub + 0x7fffu + ((ub >> 16) & 1u)) & 0xffff0000u;
  return lo | hi;
}
__device__ __forceinline__ unsigned short pk_bf16_1(float a) {
  unsigned ua = __float_as_uint(a);
  return (unsigned short)((ua + 0x7fffu + ((ua >> 16) & 1u)) >> 16);
}

// ---------------------------------------------------------------------------
// Transpose the 4 weight matrices W[j][i] -> WT[i][j].  (R9-proven; direct-W
// reads regressed 20us in R10.)
// ---------------------------------------------------------------------------
__global__ __launch_bounds__(256)
void transpose4_kernel(const float* __restrict__ W0, const float* __restrict__ W1,
                       const float* __restrict__ W2, const float* __restrict__ W3,
                       float* __restrict__ WT)
{
  const float* W = (blockIdx.y == 0) ? W0 : (blockIdx.y == 1) ? W1
                 : (blockIdx.y == 2) ? W2 : W3;
  float* out = WT + blockIdx.y * EDIM * EDIM;
  const int i0 = blockIdx.x * 16;
  #pragma unroll
  for (int it = 0; it < 8; ++it) {
    int f = threadIdx.x + it * 256;
    int i = i0 + (f >> 7);
    int j = f & 127;
    out[i * EDIM + j] = W[j * EDIM + i];
  }
}

// ---------------------------------------------------------------------------
// out = X @ W^T + b with pre-transposed WT. 32 rows x 128 cols per block.
// mode 0: Q scaled by QNEG -> bf16 [bh][s][8]
// mode 1: K -> bf16 [bh][s][8]  (coalesced uint2 stores)
// mode 2: V -> bf16 Vt[bh][d 0..8][2048] (u16 scatter; ones row d=8 merged)
// mode 3: fp32 row-major [rows][128] (final output)
// ---------------------------------------------------------------------------
__device__ __forceinline__
void proj_body(const float* __restrict__ X, const float* __restrict__ WT,
               const float* __restrict__ bias, void* __restrict__ out, int mode)
{
  __shared__ float xs[32][EDIM];                  // 16 KB
  const int tid = threadIdx.x;
  const int row0 = blockIdx.x * 32;

  const float4* src = (const float4*)(X + row0 * EDIM);
  float4* dst = (float4*)(&xs[0][0]);
  #pragma unroll
  for (int t = 0; t < 4; ++t) dst[tid + t * 256] = src[tid + t * 256];
  __syncthreads();

  const int tc = tid & 31;
  const int tr = tid >> 5;                        // 0..7 (4 rows each)
  const int col0 = tc * 4;

  float acc[4][4];
  #pragma unroll
  for (int r = 0; r < 4; ++r)
    #pragma unroll
    for (int c = 0; c < 4; ++c) acc[r][c] = 0.f;

  #pragma unroll 2
  for (int ib = 0; ib < EDIM / 4; ++ib) {
    const float4 w0 = *(const float4*)(WT + (4 * ib + 0) * EDIM + col0);
    const float4 w1 = *(const float4*)(WT + (4 * ib + 1) * EDIM + col0);
    const float4 w2 = *(const float4*)(WT + (4 * ib + 2) * EDIM + col0);
    const float4 w3 = *(const float4*)(WT + (4 * ib + 3) * EDIM + col0);
    #pragma unroll
    for (int r = 0; r < 4; ++r) {
      const float4 x4 = *(const float4*)(&xs[tr * 4 + r][ib * 4]);  // b128 broadcast
      acc[r][0] += x4.x * w0.x + x4.y * w1.x + x4.z * w2.x + x4.w * w3.x;
      acc[r][1] += x4.x * w0.y + x4.y * w1.y + x4.z * w2.y + x4.w * w3.y;
      acc[r][2] += x4.x * w0.z + x4.y * w1.z + x4.z * w2.z + x4.w * w3.z;
      acc[r][3] += x4.x * w0.w + x4.y * w1.w + x4.z * w2.w + x4.w * w3.w;
    }
  }

  const float4 b4 = *(const float4*)(bias + col0);
  #pragma unroll
  for (int r = 0; r < 4; ++r) {
    const int grow = row0 + tr * 4 + r;
    const float4 o = make_float4(acc[r][0] + b4.x, acc[r][1] + b4.y,
                                 acc[r][2] + b4.z, acc[r][3] + b4.w);
    if (mode == 3) {
      *(float4*)((float*)out + (size_t)grow * EDIM + col0) = o;
    } else {
      const int b = grow >> 11, s = grow & (SEQ - 1);
      const int h = col0 >> 3, d0 = col0 & 7;     // d0 in {0,4}
      const size_t bhs = (size_t)(b * NHEAD + h) * SEQ + s;
      if (mode == 0) {
        uint2 p;
        p.x = pk_bf16(o.x * QNEG, o.y * QNEG);
        p.y = pk_bf16(o.z * QNEG, o.w * QNEG);
        *(uint2*)((unsigned*)out + bhs * 4 + (d0 >> 1)) = p;
      } else if (mode == 1) {
        uint2 p;
        p.x = pk_bf16(o.x, o.y);
        p.y = pk_bf16(o.z, o.w);
        *(uint2*)((unsigned*)out + bhs * 4 + (d0 >> 1)) = p;
      } else {
        unsigned short* vt = (unsigned short*)out;  // Vt[bh][d 0..8][2048]
        const size_t base = (size_t)(b * NHEAD + h) * 9;
        const float oo[4] = {o.x, o.y, o.z, o.w};
        #pragma unroll
        for (int c = 0; c < 4; ++c)
          vt[(base + d0 + c) * SEQ + s] = pk_bf16_1(oo[c]);
      }
    }
  }

  if (mode == 2) {
    // ones row d=8 for this block's (b, s) range, all 16 heads (R10-proven)
    const int b0 = row0 >> 11, s0 = row0 & (SEQ - 1);
    const int hh = tid >> 4, si = tid & 15;       // 16 dwords = 32 s per head
    unsigned* vtd = (unsigned*)out;
    vtd[((size_t)(b0 * NHEAD + hh) * 9 + 8) * (SEQ / 2) + (s0 >> 1) + si] = 0x3F803F80u;
  }
}

__global__ __launch_bounds__(256)
void qkv_kernel(const float* __restrict__ X, const float* __restrict__ WT,
                const float* __restrict__ bq, const float* __restrict__ bk,
                const float* __restrict__ bv,
                unsigned* __restrict__ qb, unsigned* __restrict__ kb,
                unsigned* __restrict__ vtg)
{
  const int m = blockIdx.y;
  const float* wt   = WT + m * EDIM * EDIM;
  const float* bias = (m == 0) ? bq : (m == 1) ? bk : bv;
  void* out         = (m == 0) ? (void*)qb : (m == 1) ? (void*)kb : (void*)vtg;
  proj_body(X, wt, bias, out, m);
}

__global__ __launch_bounds__(256)
void oproj_kernel(const float* __restrict__ A, const float* __restrict__ WTo,
                  const float* __restrict__ bo, float* __restrict__ out)
{
  proj_body(A, WTo, bo, (void*)out, 3);
}

// ---------------------------------------------------------------------------
// One 16q x 16k MFMA step (out^T orientation, R7-proven).
// S^T = mfma_16x16x32_bf16(A=K-rows, B=Q-frag) -> C[key][q] (row=4*quad+reg,
// col=laneq). Sigmoid elementwise; C-layout of S^T IS the B-layout of
// mfma_16x16x16 -> PV with NO transform:
// out^T = mfma_16x16x16_bf16(A=Vt-frag [d][key], B=P^T, acc).
// Vt row d=8 = ones -> acc row 8 = denominator (rows 9..15 junk, unstored).
// ---------------------------------------------------------------------------
template<bool DIAG>
__device__ __forceinline__
float4v attn_step(short8v kf, short8v qf, short4v vf, float4v acc,
                  int laneq, int quad)
{
  const float4v z = {0.f, 0.f, 0.f, 0.f};
  float4v st = __builtin_amdgcn_mfma_f32_16x16x32_bf16(kf, qf, z, 0, 0, 0);
  unsigned rb[4];
  #pragma unroll
  for (int r = 0; r < 4; ++r) {
    float s = RCPF(1.f + EXP2F(st[r]));           // Q carries -scale*log2e
    if (DIAG) s = (4 * quad + r <= laneq) ? s : 0.f;  // exact: sigma(-1e9)==0
    rb[r] = __float_as_uint(s) + 0x8000u;         // round-half-up to bf16
  }
  U16x4 p;
  p.u.x = __builtin_amdgcn_perm(rb[1], rb[0], 0x07060302u);
  p.u.y = __builtin_amdgcn_perm(rb[3], rb[2], 0x07060302u);
  return MFMA_PV(vf, p.s, acc);                   // A = Vt[d][k], B = P^T[k][q]
}

// epilogue: den = acc row d=8 (quad 2 reg 0 -> lane 32+laneq); one bpermute
__device__ __forceinline__
void epilogue(float4v acc, int T, int bh, int laneq, int quad, int lane,
              float* __restrict__ out)
{
  const int b_ = bh >> 4, h = bh & 15;
  const int di = __builtin_amdgcn_ds_bpermute((32 + laneq) << 2,
                                              __float_as_int(acc[0]));
  const float inv = RCPF(__int_as_float(di));     // den > 0
  if (lane < 32) {                                // quads 0,1 hold d=0..7
    const float4 o = make_float4(acc[0] * inv, acc[1] * inv,
                                 acc[2] * inv, acc[3] * inv);
    const int row = 16 * T + laneq;
    *(float4*)(out + ((size_t)(b_ * SEQ + row)) * EDIM + h * HDIM + 4 * quad) = o;
  }
}

// ---------------------------------------------------------------------------
// Causal sigmoid-attention v13: 256-thr blocks (2 fold-pairs) + Vt loads.
// Each 256-thr block hosts TWO independent fold-pairs (g = 2*gg + pair);
// within a pair, 2 waves split the 129 key-tile steps (wave0: [0,mL) dual +
// [mL,mH) H-only, no diags; wave1: [mL,L] and [mH,H], both diags). Perfect
// balance; grid 2048 -> 8 blocks/CU x 4 waves = 32 waves/CU (the 128-thr
// version capped at ~8 WGs/CU = 54% occupancy). V-frag = one broadcast
// dwordx2 from Vt[bh][d][s] (no u16 packing, no is8 cndmask; ones row d=8
// gives the denominator). Scalar prefetch vars only. bh in low 6 bits of
// blockIdx -> XCD locality.
// ---------------------------------------------------------------------------
__global__ __launch_bounds__(256, 8)
void attn_kernel(const unsigned* __restrict__ Qb, const unsigned* __restrict__ Kb,
                 const unsigned* __restrict__ Vtg, float* __restrict__ out)
{
  __shared__ float cmb[2][2][64][4];              // 4 KB

  const int bh    = blockIdx.x & 63;
  const int gg    = blockIdx.x >> 6;              // 0..31
  const int tid   = threadIdx.x;
  const int pair  = tid >> 7;                     // 0/1: independent fold-pair
  const int w     = (tid >> 6) & 1;               // split-K role within pair
  const int lane  = tid & 63;
  const int laneq = lane & 15;
  const int quad  = lane >> 4;
  const int g = 2 * gg + pair;                    // 0..63
  const int L = g, H = 127 - g;
  const int mL = (L + 1) >> 1, mH = (H + 1) >> 1;

  const uint4* Qg  = (const uint4*)Qb + (size_t)bh * 2048;
  const uint4* kb0 = (const uint4*)Kb + (size_t)bh * 2048 + laneq;
  const int vrow = (laneq < 8) ? laneq : 8;       // d; rows 9..15 read ones
  const unsigned short* vb0 = (const unsigned short*)Vtg
                            + ((size_t)bh * 9 + vrow) * SEQ + 4 * quad;

  // Q B-frags: lanes<16 hold the 8-dim row (k=0..7); zero lanes>=16 (pads
  // the K=32 contraction; K-frag upper quads multiply by these zeros)
  U16x8 qfl, qfh;
  {
    const uint4 rl = Qg[16 * L + laneq];
    const uint4 rh = Qg[16 * H + laneq];
    qfl.u = (lane < 16) ? rl : make_uint4(0u, 0u, 0u, 0u);
    qfh.u = (lane < 16) ? rh : make_uint4(0u, 0u, 0u, 0u);
  }

  float4v accL = {0.f, 0.f, 0.f, 0.f};
  float4v accH = {0.f, 0.f, 0.f, 0.f};

  if (w == 0) {
    // k-tiles [0,mL) dual (L+H), [mL,mH) H-only; no diags; 1-deep prefetch
    U16x8 kf; kf.u = kb0[0];
    U16x4 vf; vf.u = *(const uint2*)(vb0);
    #pragma unroll 4
    for (int t = 0; t < mH; ++t) {
      U16x8 kn; kn.u = kb0[16 * (t + 1)];         // t+1 <= mH <= 64: in-bounds
      U16x4 vn; vn.u = *(const uint2*)(vb0 + 16 * (t + 1));
      if (t < mL) accL = attn_step<false>(kf.s, qfl.s, vf.s, accL, laneq, quad);
      accH = attn_step<false>(kf.s, qfh.s, vf.s, accH, laneq, quad);
      kf = kn; vf = vn;
    }
  } else {
    // L segment: [mL, L], diag at L
    U16x8 kf; kf.u = kb0[16 * mL];
    U16x4 vf; vf.u = *(const uint2*)(vb0 + 16 * mL);
    #pragma unroll 4
    for (int t = mL; t < L; ++t) {
      U16x8 kn; kn.u = kb0[16 * (t + 1)];
      U16x4 vn; vn.u = *(const uint2*)(vb0 + 16 * (t + 1));
      accL = attn_step<false>(kf.s, qfl.s, vf.s, accL, laneq, quad);
      kf = kn; vf = vn;
    }
    accL = attn_step<true>(kf.s, qfl.s, vf.s, accL, laneq, quad);
    // H segment: [mH, H], diag at H
    kf.u = kb0[16 * mH];
    vf.u = *(const uint2*)(vb0 + 16 * mH);
    #pragma unroll 4
    for (int t = mH; t < H; ++t) {
      U16x8 kn; kn.u = kb0[16 * (t + 1)];         // t+1 <= H = 127: in-bounds
      U16x4 vn; vn.u = *(const uint2*)(vb0 + 16 * (t + 1));
      accH = attn_step<false>(kf.s, qfh.s, vf.s, accH, laneq, quad);
      kf = kn; vf = vn;
    }
    accH = attn_step<true>(kf.s, qfh.s, vf.s, accH, laneq, quad);

    *(float4*)&cmb[pair][0][lane][0] = make_float4(accL[0], accL[1], accL[2], accL[3]);
    *(float4*)&cmb[pair][1][lane][0] = make_float4(accH[0], accH[1], accH[2], accH[3]);
  }
  __syncthreads();

  if (w == 0) {
    const float4 pL = *(const float4*)&cmb[pair][0][lane][0];
    const float4 pH = *(const float4*)&cmb[pair][1][lane][0];
    accL[0] += pL.x; accL[1] += pL.y; accL[2] += pL.z; accL[3] += pL.w;
    accH[0] += pH.x; accH[1] += pH.y; accH[2] += pH.z; accH[3] += pH.w;
    epilogue(accL, L, bh, laneq, quad, lane, out);
    epilogue(accH, H, bh, laneq, quad, lane, out);
  }
}

// ---------------------------------------------------------------------------
extern "C" void kernel_launch(void* const* d_in, const int* in_sizes, int n_in,
                              void* d_out, int out_size, void* d_ws, size_t ws_size,
                              hipStream_t stream)
{
  const float* x  = (const float*)d_in[0];
  const float* Wq = (const float*)d_in[1];
  const float* bq = (const float*)d_in[2];
  const float* Wk = (const float*)d_in[3];
  const float* bk = (const float*)d_in[4];
  const float* Wv = (const float*)d_in[5];
  const float* bv = (const float*)d_in[6];
  const float* Wo = (const float*)d_in[7];
  const float* bo = (const float*)d_in[8];

  float* ws = (float*)d_ws;
  // layout: WT 65536 f | Qb 524288 dw | Kb 524288 dw | Vtg 589824 dw | attn
  float*    WT   = ws;
  unsigned* Qb   = (unsigned*)(ws + 65536);
  unsigned* Kb   = Qb + (size_t)524288;
  unsigned* Vtg  = Kb + (size_t)524288;
  float*    attn = (float*)(Vtg + (size_t)589824);

  transpose4_kernel<<<dim3(8, 4), 256, 0, stream>>>(Wq, Wk, Wv, Wo, WT);
  qkv_kernel<<<dim3(NROW / 32, 3), 256, 0, stream>>>(x, WT, bq, bk, bv, Qb, Kb, Vtg);
  attn_kernel<<<dim3(2048), 256, 0, stream>>>(Qb, Kb, Vtg, attn);
  oproj_kernel<<<dim3(NROW / 32), 256, 0, stream>>>(attn, WT + 3 * EDIM * EDIM, bo,
                                                    (float*)d_out);
}

// Round 14
// 158.705 us; speedup vs baseline: 1.0671x; 1.0671x over previous
//
#include <hip/hip_runtime.h>
#include <math.h>

#define EDIM 128
#define NHEAD 16
#define HDIM 8
#define SEQ 2048
#define BATCH 4
#define NROW (BATCH*SEQ)            // 8192
// -scale*log2(e): folded into Q at projection time so sigmoid = rcp(1+exp2(dot))
#define QNEG (-0.35355339059327373f * 1.4426950408889634f)

#if __has_builtin(__builtin_amdgcn_exp2f)
#define EXP2F(x) __builtin_amdgcn_exp2f(x)
#else
#define EXP2F(x) exp2f(x)
#endif
#define RCPF(x) __builtin_amdgcn_rcpf(x)

typedef __attribute__((ext_vector_type(8))) short short8v;
typedef __attribute__((ext_vector_type(4))) short short4v;
typedef __attribute__((ext_vector_type(4))) float float4v;

union U16x8 { uint4 u; short8v s; };
union U16x4 { uint2 u; short4v s; };

#if __has_builtin(__builtin_amdgcn_mfma_f32_16x16x16bf16_1k)
#define MFMA_PV(a,b,c) __builtin_amdgcn_mfma_f32_16x16x16bf16_1k(a,b,c,0,0,0)
#else
static __device__ __forceinline__ float4v mfma_pv_asm(short4v a, short4v b, float4v c) {
  float4v d;
  asm("v_mfma_f32_16x16x16_bf16 %0, %1, %2, %3" : "=v"(d) : "v"(a), "v"(b), "v"(c));
  return d;
}
#define MFMA_PV(a,b,c) mfma_pv_asm(a,b,c)
#endif

// pack two floats to bf16x2, round-to-nearest-even (values finite)
__device__ __forceinline__ unsigned pk_bf16(float a, float b) {
  unsigned ua = __float_as_uint(a), ub = __float_as_uint(b);
  unsigned lo = (ua + 0x7fffu + ((ua >> 16) & 1u)) >> 16;
  unsigned hi = (ub + 0x7fffu + ((ub >> 16) & 1u)) & 0xffff0000u;
  return lo | hi;
}

// ---------------------------------------------------------------------------
// Transpose the 4 weight matrices W[j][i] -> WT[i][j].  (R9/R12-proven;
// direct-W reads regressed 20us in R10.)
// ---------------------------------------------------------------------------
__global__ __launch_bounds__(256)
void transpose4_kernel(const float* __restrict__ W0, const float* __restrict__ W1,
                       const float* __restrict__ W2, const float* __restrict__ W3,
                       float* __restrict__ WT)
{
  const float* W = (blockIdx.y == 0) ? W0 : (blockIdx.y == 1) ? W1
                 : (blockIdx.y == 2) ? W2 : W3;
  float* out = WT + blockIdx.y * EDIM * EDIM;
  const int i0 = blockIdx.x * 16;
  #pragma unroll
  for (int it = 0; it < 8; ++it) {
    int f = threadIdx.x + it * 256;
    int i = i0 + (f >> 7);
    int j = f & 127;
    out[i * EDIM + j] = W[j * EDIM + i];
  }
}

// ---------------------------------------------------------------------------
// out = X @ W^T + b with pre-transposed WT. 32 rows x 128 cols per block.
// mode 0: Q scaled by QNEG -> bf16 [bh][s][8]
// mode 1/2: K / V -> bf16 [bh][s][8]  (coalesced uint2 stores; the dense
//   V[s][8] layout beat Vt[d][s] broadcast loads in R10/R13 A/B tests)
// mode 3: fp32 row-major [rows][128] (final output)
// ---------------------------------------------------------------------------
__device__ __forceinline__
void proj_body(const float* __restrict__ X, const float* __restrict__ WT,
               const float* __restrict__ bias, void* __restrict__ out, int mode)
{
  __shared__ float xs[32][EDIM];                  // 16 KB
  const int tid = threadIdx.x;
  const int row0 = blockIdx.x * 32;

  const float4* src = (const float4*)(X + row0 * EDIM);
  float4* dst = (float4*)(&xs[0][0]);
  #pragma unroll
  for (int t = 0; t < 4; ++t) dst[tid + t * 256] = src[tid + t * 256];
  __syncthreads();

  const int tc = tid & 31;
  const int tr = tid >> 5;                        // 0..7 (4 rows each)
  const int col0 = tc * 4;

  float acc[4][4];
  #pragma unroll
  for (int r = 0; r < 4; ++r)
    #pragma unroll
    for (int c = 0; c < 4; ++c) acc[r][c] = 0.f;

  #pragma unroll 2
  for (int ib = 0; ib < EDIM / 4; ++ib) {
    const float4 w0 = *(const float4*)(WT + (4 * ib + 0) * EDIM + col0);
    const float4 w1 = *(const float4*)(WT + (4 * ib + 1) * EDIM + col0);
    const float4 w2 = *(const float4*)(WT + (4 * ib + 2) * EDIM + col0);
    const float4 w3 = *(const float4*)(WT + (4 * ib + 3) * EDIM + col0);
    #pragma unroll
    for (int r = 0; r < 4; ++r) {
      const float4 x4 = *(const float4*)(&xs[tr * 4 + r][ib * 4]);  // b128 broadcast
      acc[r][0] += x4.x * w0.x + x4.y * w1.x + x4.z * w2.x + x4.w * w3.x;
      acc[r][1] += x4.x * w0.y + x4.y * w1.y + x4.z * w2.y + x4.w * w3.y;
      acc[r][2] += x4.x * w0.z + x4.y * w1.z + x4.z * w2.z + x4.w * w3.z;
      acc[r][3] += x4.x * w0.w + x4.y * w1.w + x4.z * w2.w + x4.w * w3.w;
    }
  }

  const float4 b4 = *(const float4*)(bias + col0);
  #pragma unroll
  for (int r = 0; r < 4; ++r) {
    const int grow = row0 + tr * 4 + r;
    const float4 o = make_float4(acc[r][0] + b4.x, acc[r][1] + b4.y,
                                 acc[r][2] + b4.z, acc[r][3] + b4.w);
    if (mode == 3) {
      *(float4*)((float*)out + (size_t)grow * EDIM + col0) = o;
    } else {
      const int b = grow >> 11, s = grow & (SEQ - 1);
      const int h = col0 >> 3, d0 = col0 & 7;     // d0 in {0,4}
      const size_t bhs = (size_t)(b * NHEAD + h) * SEQ + s;
      uint2 p;
      if (mode == 0) {
        p.x = pk_bf16(o.x * QNEG, o.y * QNEG);
        p.y = pk_bf16(o.z * QNEG, o.w * QNEG);
      } else {
        p.x = pk_bf16(o.x, o.y);
        p.y = pk_bf16(o.z, o.w);
      }
      *(uint2*)((unsigned*)out + bhs * 4 + (d0 >> 1)) = p;
    }
  }
}

__global__ __launch_bounds__(256)
void qkv_kernel(const float* __restrict__ X, const float* __restrict__ WT,
                const float* __restrict__ bq, const float* __restrict__ bk,
                const float* __restrict__ bv,
                unsigned* __restrict__ qb, unsigned* __restrict__ kb,
                unsigned* __restrict__ vb)
{
  const int m = blockIdx.y;
  const float* wt   = WT + m * EDIM * EDIM;
  const float* bias = (m == 0) ? bq : (m == 1) ? bk : bv;
  void* out         = (m == 0) ? (void*)qb : (m == 1) ? (void*)kb : (void*)vb;
  proj_body(X, wt, bias, out, m);
}

__global__ __launch_bounds__(256)
void oproj_kernel(const float* __restrict__ A, const float* __restrict__ WTo,
                  const float* __restrict__ bo, float* __restrict__ out)
{
  proj_body(A, WTo, bo, (void*)out, 3);
}

// ---------------------------------------------------------------------------
// One 16q x 16k MFMA step (R12-proven orientation).
// S^T = mfma_16x16x32_bf16(A=K-rows, B=Q-frag) -> C[key][q]. Sigmoid
// elementwise. C reinterpreted as A-operand of mfma_16x16x16 reads
// A[m=laneq][k=4*quad+j] = S[q][key], so out[q][d] = mfma(A=P, B=V-frag, acc)
// directly. V-frag col n=8 forced to 1.0 -> acc col 8 = denominator.
// ---------------------------------------------------------------------------
template<bool DIAG>
__device__ __forceinline__
float4v attn_step(short8v kf, short8v qf, short4v vf, float4v acc,
                  int laneq, int quad)
{
  const float4v z = {0.f, 0.f, 0.f, 0.f};
  float4v st = __builtin_amdgcn_mfma_f32_16x16x32_bf16(kf, qf, z, 0, 0, 0);
  unsigned rb[4];
  #pragma unroll
  for (int r = 0; r < 4; ++r) {
    float s = RCPF(1.f + EXP2F(st[r]));           // Q carries -scale*log2e
    if (DIAG) s = (4 * quad + r <= laneq) ? s : 0.f;  // exact: sigma(-1e9)==0
    rb[r] = __float_as_uint(s) + 0x8000u;         // round-half-up to bf16
  }
  U16x4 p;
  p.u.x = __builtin_amdgcn_perm(rb[1], rb[0], 0x07060302u);
  p.u.y = __builtin_amdgcn_perm(rb[3], rb[2], 0x07060302u);
  return MFMA_PV(p.s, vf, acc);                   // A = P[q][k], B = V[k][d]
}

// V-frag loader from a per-lane base pointer: element (16t+4q+i)*8+d
// = vb0[128t + 8i] with vb0 = Vbh + 32*quad + d  ->  affine-in-t addresses.
// laneq==8 lanes -> bf16 1.0 (denominator column).
__device__ __forceinline__
short4v load_vfrag(const unsigned short* __restrict__ vb0, int t, bool is8)
{
  const unsigned short* p = vb0 + 128 * t;
  const unsigned v0 = p[0];
  const unsigned v1 = p[8];
  const unsigned v2 = p[16];
  const unsigned v3 = p[24];
  U16x4 vf;
  vf.u.x = is8 ? 0x3F803F80u : (v0 | (v1 << 16));
  vf.u.y = is8 ? 0x3F803F80u : (v2 | (v3 << 16));
  return vf.s;
}

// epilogue: den = acc col 8; normalize and store rows of tile T
__device__ __forceinline__
void epilogue(float4v acc, int T, int bh, int laneq, int quad,
              float* __restrict__ out)
{
  const int b_ = bh >> 4, h = bh & 15;
  const int pidx = (quad * 16 + 8) << 2;          // lane holding col 8
  #pragma unroll
  for (int r = 0; r < 4; ++r) {
    const float den = __int_as_float(
        __builtin_amdgcn_ds_bpermute(pidx, __float_as_int(acc[r])));
    const float val = acc[r] * RCPF(den);         // den > 0
    const int row = 16 * T + 4 * quad + r;
    if (laneq < 8)
      out[(size_t)(b_ * SEQ + row) * EDIM + h * HDIM + laneq] = val;
  }
}

// ---------------------------------------------------------------------------
// Causal sigmoid-attention v14: R12 hot loop, 256-thr 2-pair blocks.
// Each 256-thr block hosts TWO independent fold-pairs (g = 2*gg + pair);
// within a pair, 2 waves split the 129 key-tile steps (wave0: [0,mL) dual +
// [mL,mH) H-only, no diags; wave1: [mL,L] + [mH,H], both diags). Perfect
// balance. Grid 2048 -> targets 8 blocks/CU x 4 waves (R12's 128-thr blocks
// capped at ~54% occupancy via the WG-slot limit). Dense V[s][8] u16 loads
// (Vt[d][s] regressed in R10/R13); scalar prefetch vars only (R11's array
// chunking spilled to scratch). bh in low 6 bits -> XCD locality.
// ---------------------------------------------------------------------------
__global__ __launch_bounds__(256, 8)
void attn_kernel(const unsigned* __restrict__ Qb, const unsigned* __restrict__ Kb,
                 const unsigned* __restrict__ Vb, float* __restrict__ out)
{
  __shared__ float cmb[2][2][64][4];              // 4 KB

  const int bh    = blockIdx.x & 63;
  const int gg    = blockIdx.x >> 6;              // 0..31
  const int tid   = threadIdx.x;
  const int pair  = tid >> 7;                     // 0/1: independent fold-pair
  const int w     = (tid >> 6) & 1;               // split-K role within pair
  const int lane  = tid & 63;
  const int laneq = lane & 15;
  const int quad  = lane >> 4;
  const int g = 2 * gg + pair;                    // 0..63
  const int L = g, H = 127 - g;
  const int mL = (L + 1) >> 1, mH = (H + 1) >> 1;
  const int d   = laneq & 7;
  const bool is8 = (laneq == 8);

  const uint4* Qg = (const uint4*)Qb + (size_t)bh * 2048;
  // per-lane affine bases: K element = kb0[16t], V element = vb0[128t + 8i]
  const uint4* kb0 = (const uint4*)Kb + (size_t)bh * 2048 + laneq;
  const unsigned short* vb0 = (const unsigned short*)Vb
                            + (size_t)bh * 2048 * 8 + 32 * quad + d;

  // Q B-frags: lanes<16 hold the 8-dim row in quad 0 (k=0..7); zero others
  U16x8 qfl, qfh;
  {
    const uint4 rl = Qg[16 * L + laneq];
    const uint4 rh = Qg[16 * H + laneq];
    qfl.u = (lane < 16) ? rl : make_uint4(0u, 0u, 0u, 0u);
    qfh.u = (lane < 16) ? rh : make_uint4(0u, 0u, 0u, 0u);
  }

  float4v accL = {0.f, 0.f, 0.f, 0.f};
  float4v accH = {0.f, 0.f, 0.f, 0.f};

  if (w == 0) {
    // k-tiles [0,mL) dual (L+H), [mL,mH) H-only; no diags; 1-deep prefetch
    U16x8 kf; kf.u = kb0[0];
    short4v vf = load_vfrag(vb0, 0, is8);
    #pragma unroll 4
    for (int t = 0; t < mH; ++t) {
      U16x8 kn; kn.u = kb0[16 * (t + 1)];         // t+1 <= mH <= 64: in-bounds
      short4v vn = load_vfrag(vb0, t + 1, is8);
      if (t < mL) accL = attn_step<false>(kf.s, qfl.s, vf, accL, laneq, quad);
      accH = attn_step<false>(kf.s, qfh.s, vf, accH, laneq, quad);
      kf = kn; vf = vn;
    }
  } else {
    // L segment: [mL, L], diag at L
    U16x8 kf; kf.u = kb0[16 * mL];
    short4v vf = load_vfrag(vb0, mL, is8);
    #pragma unroll 4
    for (int t = mL; t < L; ++t) {
      U16x8 kn; kn.u = kb0[16 * (t + 1)];
      short4v vn = load_vfrag(vb0, t + 1, is8);
      accL = attn_step<false>(kf.s, qfl.s, vf, accL, laneq, quad);
      kf = kn; vf = vn;
    }
    accL = attn_step<true>(kf.s, qfl.s, vf, accL, laneq, quad);
    // H segment: [mH, H], diag at H
    kf.u = kb0[16 * mH];
    vf = load_vfrag(vb0, mH, is8);
    #pragma unroll 4
    for (int t = mH; t < H; ++t) {
      U16x8 kn; kn.u = kb0[16 * (t + 1)];         // t+1 <= H = 127: in-bounds
      short4v vn = load_vfrag(vb0, t + 1, is8);
      accH = attn_step<false>(kf.s, qfh.s, vf, accH, laneq, quad);
      kf = kn; vf = vn;
    }
    accH = attn_step<true>(kf.s, qfh.s, vf, accH, laneq, quad);

    *(float4*)&cmb[pair][0][lane][0] = make_float4(accL[0], accL[1], accL[2], accL[3]);
    *(float4*)&cmb[pair][1][lane][0] = make_float4(accH[0], accH[1], accH[2], accH[3]);
  }
  __syncthreads();

  if (w == 0) {
    const float4 pL = *(const float4*)&cmb[pair][0][lane][0];
    const float4 pH = *(const float4*)&cmb[pair][1][lane][0];
    accL[0] += pL.x; accL[1] += pL.y; accL[2] += pL.z; accL[3] += pL.w;
    accH[0] += pH.x; accH[1] += pH.y; accH[2] += pH.z; accH[3] += pH.w;
    epilogue(accL, L, bh, laneq, quad, out);
    epilogue(accH, H, bh, laneq, quad, out);
  }
}

// ---------------------------------------------------------------------------
extern "C" void kernel_launch(void* const* d_in, const int* in_sizes, int n_in,
                              void* d_out, int out_size, void* d_ws, size_t ws_size,
                              hipStream_t stream)
{
  const float* x  = (const float*)d_in[0];
  const float* Wq = (const float*)d_in[1];
  const float* bq = (const float*)d_in[2];
  const float* Wk = (const float*)d_in[3];
  const float* bk = (const float*)d_in[4];
  const float* Wv = (const float*)d_in[5];
  const float* bv = (const float*)d_in[6];
  const float* Wo = (const float*)d_in[7];
  const float* bo = (const float*)d_in[8];

  float* ws = (float*)d_ws;
  // layout: WT 65536 f | attn 1048576 f | Qb, Kb, Vb 524288 dwords each
  float*    WT   = ws;
  float*    attn = ws + 65536;
  unsigned* Qb   = (unsigned*)(ws + 65536 + 1048576);
  unsigned* Kb   = Qb + (size_t)524288;
  unsigned* Vb   = Kb + (size_t)524288;

  transpose4_kernel<<<dim3(8, 4), 256, 0, stream>>>(Wq, Wk, Wv, Wo, WT);
  qkv_kernel<<<dim3(NROW / 32, 3), 256, 0, stream>>>(x, WT, bq, bk, bv, Qb, Kb, Vb);
  attn_kernel<<<dim3(2048), 256, 0, stream>>>(Qb, Kb, Vb, attn);
  oproj_kernel<<<dim3(NROW / 32), 256, 0, stream>>>(attn, WT + 3 * EDIM * EDIM, bo,
                                                    (float*)d_out);
}